// Round 10
// baseline (31.435 us; speedup 1.0000x reference)
//
#include <hip/hip_runtime.h>
#include <hip/hip_fp16.h>

// DeformConv2d: x[8,64,56,56], offset[8,18,56,56], weight[64,64,3,3] -> out[8,64,56,56]
// prep (NHWC fp16 x + swizzled fp16 w) -> barrier-free 1-wave fused gather+MFMA.
// Wave = 16 px x 64 oc. B-fragments gathered directly into registers (lane mapping of
// the gather unit == MFMA B-fragment layout). No LDS, no __syncthreads in fused kernel,
// so staged loads are never drained by the compiler's pre-barrier vmcnt(0).

typedef _Float16 f16x8 __attribute__((ext_vector_type(8)));
typedef float    f32x4 __attribute__((ext_vector_type(4)));

namespace {
constexpr int Bn = 8, Cn = 64, Hn = 56, Wn = 56;
constexpr int Kk = 9, OCn = 64;
constexpr int NPIX = 56 * 56;      // 3136
constexpr int CK   = Cn * Kk;      // 576
constexpr int KSTEPS = CK / 32;    // 18
constexpr int TPW  = 16;           // px per wave (= per block)
constexpr int TILES = NPIX / TPW;  // 196
constexpr int XTILES = NPIX / 64;  // 49 (prep transpose tiles)
}

__device__ __forceinline__ __half2 u2h(unsigned u) {
    union { unsigned u; __half2 h; } x; x.u = u; return x.h;
}
__device__ __forceinline__ unsigned bcast_h(float f) {
    unsigned short hs = __half_as_ushort(__float2half(f));
    return (unsigned)hs * 0x10001u;
}

// prep: blocks [0,392): x NCHW fp32 -> NHWC fp16. blocks [392,536): w -> wh2 A-frag layout.
// wh2 uint4 index ((og*18+ks)*64+lane) = w[oc=og*16+(lane&15)][kglob=ks*32+(lane>>4)*8+j],
// kglob = tap*64 + c.
__global__ __launch_bounds__(256) void prep_kernel(
    const float* __restrict__ x, const float* __restrict__ w,
    unsigned short* __restrict__ xh, unsigned short* __restrict__ wh2)
{
    const int tid = threadIdx.x;
    if (blockIdx.x >= 392) {
        const int i = (blockIdx.x - 392) * 256 + tid;
        if (i < OCn * CK) {
            const int j    = i & 7;
            const int lane = (i >> 3) & 63;
            const int rest = i >> 9;           // og*18 + ks
            const int og   = rest / KSTEPS;
            const int oc   = og * 16 + (lane & 15);
            const int kglob = (rest % KSTEPS) * 32 + (lane >> 4) * 8 + j;
            const int tap = kglob >> 6;
            const int c   = kglob & 63;
            wh2[i] = __half_as_ushort(__float2half(w[oc * CK + c * Kk + tap]));
        }
        return;
    }
    __shared__ unsigned short lds[64][66];
    const int b  = blockIdx.x / XTILES;
    const int t0 = (blockIdx.x % XTILES) * 64;
    const float* xb = x + (size_t)b * Cn * NPIX;
    {
        const int hw0 = (tid & 15) * 4;
        #pragma unroll
        for (int i = 0; i < 4; ++i) {
            const int c = (tid >> 4) + i * 16;
            const float4 v = *(const float4*)(xb + (size_t)c * NPIX + t0 + hw0);
            lds[hw0 + 0][c] = __half_as_ushort(__float2half(v.x));
            lds[hw0 + 1][c] = __half_as_ushort(__float2half(v.y));
            lds[hw0 + 2][c] = __half_as_ushort(__float2half(v.z));
            lds[hw0 + 3][c] = __half_as_ushort(__float2half(v.w));
        }
    }
    __syncthreads();
    {
        const int co = (tid & 7) * 8;
        #pragma unroll
        for (int i = 0; i < 2; ++i) {
            const int hw = (tid >> 3) + i * 32;
            unsigned short tmp[8] __attribute__((aligned(16)));
            #pragma unroll
            for (int j = 0; j < 8; ++j) tmp[j] = lds[hw][co + j];
            *(uint4*)(xh + ((size_t)b * NPIX + t0 + hw) * Cn + co) = *(const uint4*)tmp;
        }
    }
}

// Fused: 1 wave per block, 16 px x 64 oc, barrier-free register pipeline.
__global__ __launch_bounds__(64, 2) void deform_fused(
    const unsigned short* __restrict__ xh, const float* __restrict__ off,
    const unsigned short* __restrict__ wh2, float* __restrict__ out)
{
    const int lane = threadIdx.x;        // 0..63
    const int lr   = lane & 15;          // px within tile; A row (oc); B/D col
    const int hi   = lane >> 4;          // k-octet group
    const int b  = blockIdx.x / TILES;
    const int p0 = (blockIdx.x % TILES) * TPW;
    const int p  = p0 + lr;
    const int oy = p / Wn, ox = p % Wn;

    const unsigned short* xb = xh + (size_t)b * NPIX * Cn;
    const float* offp = off + (size_t)b * 18 * NPIX + p;
    const uint4* ab = (const uint4*)wh2 + lane;

    // all 18 offset scalars upfront (independent, in flight together)
    float offv[18];
    #pragma unroll
    for (int t = 0; t < 18; ++t) offv[t] = offp[(size_t)t * NPIX];

    unsigned wqs[2][4];     // bilinear weights, slot = tap&1
    int4     avs[2];        // corner offsets (halves), slot = tap&1
    uint4 aF[2][4];         // A prefetch, slot = ks&1
    uint4 s0[3], s1[3], s2[3], s3[3];   // corner staging, slot = ks%3
    f32x4 acc[4] = {{0.f,0.f,0.f,0.f},{0.f,0.f,0.f,0.f},
                    {0.f,0.f,0.f,0.f},{0.f,0.f,0.f,0.f}};

    auto meta = [&](int t) {             // compute sampling metadata for tap t
        const int sl = t & 1;
        const int ki = t / 3, kj = t % 3;
        const float py  = offv[2*t]   + (float)(oy - 1 + ki);
        const float pxv = offv[2*t+1] + (float)(ox - 1 + kj);
        const float y0f = floorf(py), x0f = floorf(pxv);
        const float ty = py - y0f, tx = pxv - x0f;
        const int y0 = (int)y0f, x0 = (int)x0f;
        const int y1 = y0 + 1, x1 = x0 + 1;
        const bool vy0 = (y0 >= 0) & (y0 < Hn);
        const bool vy1 = (y1 >= 0) & (y1 < Hn);
        const bool vx0 = (x0 >= 0) & (x0 < Wn);
        const bool vx1 = (x1 >= 0) & (x1 < Wn);
        const int cy0 = min(max(y0, 0), Hn - 1);
        const int cy1 = min(max(y1, 0), Hn - 1);
        const int cx0 = min(max(x0, 0), Wn - 1);
        const int cx1 = min(max(x1, 0), Wn - 1);
        wqs[sl][0] = bcast_h((vy0 && vx0) ? (1.f - ty) * (1.f - tx) : 0.f);
        wqs[sl][1] = bcast_h((vy0 && vx1) ? (1.f - ty) * tx         : 0.f);
        wqs[sl][2] = bcast_h((vy1 && vx0) ? ty * (1.f - tx)         : 0.f);
        wqs[sl][3] = bcast_h((vy1 && vx1) ? ty * tx                 : 0.f);
        avs[sl].x = (cy0 * Wn + cx0) * Cn;
        avs[sl].y = (cy0 * Wn + cx1) * Cn;
        avs[sl].z = (cy1 * Wn + cx0) * Cn;
        avs[sl].w = (cy1 * Wn + cx1) * Cn;
    };
    auto stage = [&](int ks) {           // issue 4 corner loads for kstep ks
        const int sl = ks % 3;
        const int4 av = avs[(ks >> 1) & 1];
        const int co = (hi + (ks & 1) * 4) * 8;
        s0[sl] = *(const uint4*)(xb + av.x + co);
        s1[sl] = *(const uint4*)(xb + av.y + co);
        s2[sl] = *(const uint4*)(xb + av.z + co);
        s3[sl] = *(const uint4*)(xb + av.w + co);
    };
    auto loadA = [&](int ks) {
        const int sl = ks & 1;
        #pragma unroll
        for (int og = 0; og < 4; ++og)
            aF[sl][og] = ab[(og * KSTEPS + ks) * 64];
    };

    // prologue: A(0) + 3 k-steps of corner loads in flight
    loadA(0);
    meta(0);
    stage(0);
    stage(1);
    meta(1);
    stage(2);

    #pragma unroll
    for (int ks = 0; ks < KSTEPS; ++ks) {
        // blend kstep ks -> B fragment (waits only on slot ks%3 loads)
        const int sl = ks % 3;
        const unsigned* wq = wqs[(ks >> 1) & 1];
        const __half2 w00 = u2h(wq[0]), w01 = u2h(wq[1]);
        const __half2 w10 = u2h(wq[2]), w11 = u2h(wq[3]);
        union { unsigned u[4]; f16x8 h; } bf;
        #pragma unroll
        for (int q = 0; q < 4; ++q) {
            __half2 a = __hmul2(w00, u2h(((const unsigned*)&s0[sl])[q]));
            a = __hfma2(w01, u2h(((const unsigned*)&s1[sl])[q]), a);
            a = __hfma2(w10, u2h(((const unsigned*)&s2[sl])[q]), a);
            a = __hfma2(w11, u2h(((const unsigned*)&s3[sl])[q]), a);
            bf.u[q] = *(const unsigned*)&a;
        }
        // refill pipeline (slot now free; loads fly under the MFMAs below)
        if (ks + 3 < KSTEPS) {
            if (((ks + 3) & 1) == 0) meta((ks + 3) >> 1);
            stage(ks + 3);
        }
        if (ks + 1 < KSTEPS) loadA(ks + 1);
        // 4 MFMAs: all 64 oc for this kstep
        #pragma unroll
        for (int og = 0; og < 4; ++og) {
            union { uint4 u; f16x8 h; } a;
            a.u = aF[ks & 1][og];
            acc[og] = __builtin_amdgcn_mfma_f32_16x16x32_f16(a.h, bf.h, acc[og], 0, 0, 0);
        }
    }

    // D: col(px)=lr, row(oc within og-16)=hi*4+r
    #pragma unroll
    for (int og = 0; og < 4; ++og) {
        float* ob = out + ((size_t)b * OCn + og * 16 + hi * 4) * NPIX + p0 + lr;
        #pragma unroll
        for (int r = 0; r < 4; ++r) ob[(size_t)r * NPIX] = acc[og][r];
    }
}

extern "C" void kernel_launch(void* const* d_in, const int* in_sizes, int n_in,
                              void* d_out, int out_size, void* d_ws, size_t ws_size,
                              hipStream_t stream) {
    const float* x   = (const float*)d_in[0];
    const float* off = (const float*)d_in[1];
    const float* w   = (const float*)d_in[2];
    float* out = (float*)d_out;
    unsigned short* wh2 = (unsigned short*)d_ws;                    // 73728 B
    unsigned short* xh  = (unsigned short*)((char*)d_ws + 131072);  // 3.21 MB

    hipLaunchKernelGGL(prep_kernel, dim3(392 + 144), dim3(256), 0, stream, x, w, xh, wh2);
    hipLaunchKernelGGL(deform_fused, dim3(Bn * TILES), dim3(64), 0, stream,
                       xh, off, wh2, out);
}

// Round 11
// 21.674 us; speedup vs baseline: 1.4503x; 1.4503x over previous
//
#include <hip/hip_runtime.h>
#include <hip/hip_fp16.h>

// DeformConv2d: x[8,64,56,56], offset[8,18,56,56], weight[64,64,3,3] -> out[8,64,56,56]
// prep (NHWC fp16 x + swizzled fp16 w) -> fused 1-tap-chunk depth-3 pipelined gather+MFMA.
// K ordering tap-major: kglob = tap*64 + c. Chunk = 1 tap (2 K-steps of 32).
// r11 change vs r9: raw s_barrier + lgkmcnt(0)-only drain (staged VGPR global loads
// stay in flight across chunk barriers; __syncthreads would vmcnt(0)-drain them).

typedef _Float16 f16x8 __attribute__((ext_vector_type(8)));
typedef float    f32x4 __attribute__((ext_vector_type(4)));

namespace {
constexpr int Bn = 8, Cn = 64, Hn = 56, Wn = 56;
constexpr int Kk = 9, OCn = 64;
constexpr int NPIX = 56 * 56;      // 3136
constexpr int CK   = Cn * Kk;      // 576
constexpr int TP   = 32;           // px per block
constexpr int TILES = NPIX / TP;   // 98
constexpr int XTILES = NPIX / 64;  // 49 (prep transpose tiles)
constexpr int KSTEPS = CK / 32;    // 18
}

__device__ __forceinline__ __half2 u2h(unsigned u) {
    union { unsigned u; __half2 h; } x; x.u = u; return x.h;
}
__device__ __forceinline__ unsigned bcast_h(float f) {
    unsigned short hs = __half_as_ushort(__float2half(f));
    return (unsigned)hs * 0x10001u;
}
// Barrier that drains ONLY LDS ops (lgkmcnt), leaving global loads (vmcnt) in flight.
__device__ __forceinline__ void lds_barrier() {
    asm volatile("s_waitcnt lgkmcnt(0)" ::: "memory");
    __builtin_amdgcn_s_barrier();
}

// prep: blocks [0,392): x NCHW fp32 -> NHWC fp16. blocks [392,536): w -> wh2 A-frag layout.
// wh2 uint4 index ((og*18+kk)*64+lane) = w[oc=og*16+(lane&15)][kglob=kk*32+(lane>>4)*8+j],
// kglob = tap*64 + c.
__global__ __launch_bounds__(256) void prep_kernel(
    const float* __restrict__ x, const float* __restrict__ w,
    unsigned short* __restrict__ xh, unsigned short* __restrict__ wh2)
{
    const int tid = threadIdx.x;
    if (blockIdx.x >= 392) {
        const int i = (blockIdx.x - 392) * 256 + tid;
        if (i < OCn * CK) {
            const int j    = i & 7;
            const int lane = (i >> 3) & 63;
            const int rest = i >> 9;           // og*18 + kk
            const int og   = rest / KSTEPS;
            const int oc   = og * 16 + (lane & 15);
            const int kglob = (rest % KSTEPS) * 32 + (lane >> 4) * 8 + j;
            const int tap = kglob >> 6;
            const int c   = kglob & 63;
            wh2[i] = __half_as_ushort(__float2half(w[oc * CK + c * Kk + tap]));
        }
        return;
    }
    __shared__ unsigned short lds[64][66];
    const int b  = blockIdx.x / XTILES;
    const int t0 = (blockIdx.x % XTILES) * 64;
    const float* xb = x + (size_t)b * Cn * NPIX;
    {
        const int hw0 = (tid & 15) * 4;
        #pragma unroll
        for (int i = 0; i < 4; ++i) {
            const int c = (tid >> 4) + i * 16;
            const float4 v = *(const float4*)(xb + (size_t)c * NPIX + t0 + hw0);
            lds[hw0 + 0][c] = __half_as_ushort(__float2half(v.x));
            lds[hw0 + 1][c] = __half_as_ushort(__float2half(v.y));
            lds[hw0 + 2][c] = __half_as_ushort(__float2half(v.z));
            lds[hw0 + 3][c] = __half_as_ushort(__float2half(v.w));
        }
    }
    __syncthreads();
    {
        const int co = (tid & 7) * 8;
        #pragma unroll
        for (int i = 0; i < 2; ++i) {
            const int hw = (tid >> 3) + i * 32;
            unsigned short tmp[8] __attribute__((aligned(16)));
            #pragma unroll
            for (int j = 0; j < 8; ++j) tmp[j] = lds[hw][co + j];
            *(uint4*)(xh + ((size_t)b * NPIX + t0 + hw) * Cn + co) = *(const uint4*)tmp;
        }
    }
}

// Fused: block = 32 px x 64 oc, 256 threads, 1-tap chunks, depth-3 gather pipeline,
// triple-buffered LDS v, depth-1 A prefetch, one raw-lgkm barrier per chunk.
__global__ __launch_bounds__(256, 4) void deform_fused(
    const unsigned short* __restrict__ xh, const float* __restrict__ off,
    const unsigned short* __restrict__ wh2, float* __restrict__ out)
{
    __shared__ uint4 smpw[Kk * TP];            // 4608 B
    __shared__ int4  smpa[Kk * TP];            // 4608 B
    __shared__ __align__(16) uint4 vbuf[3][8 * TP];   // 12288 B

    const int tid = threadIdx.x;
    const int b  = blockIdx.x / TILES;
    const int p0 = (blockIdx.x % TILES) * TP;
    const unsigned short* xb = xh + (size_t)b * NPIX * Cn;
    const float* offb = off + (size_t)b * 18 * NPIX;

    // ---- metadata: entry per (tap, px), 288 entries ----
    for (int e = tid; e < Kk * TP; e += 256) {
        const int k  = e >> 5;
        const int px = e & 31;
        const int p  = p0 + px;
        const int oy = p / Wn, ox = p % Wn;
        const int ki = k / 3, kj = k % 3;
        const float offy = offb[(size_t)(2 * k)     * NPIX + p];
        const float offx = offb[(size_t)(2 * k + 1) * NPIX + p];
        const float py  = offy + (float)(oy - 1 + ki);
        const float pxv = offx + (float)(ox - 1 + kj);
        const float y0f = floorf(py), x0f = floorf(pxv);
        const float ty = py - y0f, tx = pxv - x0f;
        const int y0 = (int)y0f, x0 = (int)x0f;
        const int y1 = y0 + 1, x1 = x0 + 1;
        const bool vy0 = (y0 >= 0) & (y0 < Hn);
        const bool vy1 = (y1 >= 0) & (y1 < Hn);
        const bool vx0 = (x0 >= 0) & (x0 < Wn);
        const bool vx1 = (x1 >= 0) & (x1 < Wn);
        const int cy0 = min(max(y0, 0), Hn - 1);
        const int cy1 = min(max(y1, 0), Hn - 1);
        const int cx0 = min(max(x0, 0), Wn - 1);
        const int cx1 = min(max(x1, 0), Wn - 1);
        uint4 wq;
        wq.x = bcast_h((vy0 && vx0) ? (1.f - ty) * (1.f - tx) : 0.f);
        wq.y = bcast_h((vy0 && vx1) ? (1.f - ty) * tx         : 0.f);
        wq.z = bcast_h((vy1 && vx0) ? ty * (1.f - tx)         : 0.f);
        wq.w = bcast_h((vy1 && vx1) ? ty * tx                 : 0.f);
        int4 av;
        av.x = (cy0 * Wn + cx0) * Cn;
        av.y = (cy0 * Wn + cx1) * Cn;
        av.z = (cy1 * Wn + cx0) * Cn;
        av.w = (cy1 * Wn + cx1) * Cn;
        smpw[e] = wq;
        smpa[e] = av;
    }
    lds_barrier();

    // thread -> gather unit (fixed): oct = tid&7, px = (tid>>3)&31
    const int oct = tid & 7;
    const int gpx = (tid >> 3) & 31;
    const int co  = oct * 8;

    // GEMM ids: wave = og (16 oc) x 32 px
    const int lane = tid & 63;
    const int og   = tid >> 6;
    const int hi   = lane >> 4;
    const int lr   = lane & 15;
    const uint4* ab = (const uint4*)wh2 + (size_t)og * KSTEPS * 64 + lane;

    uint4 s0[3], s1[3], s2[3], s3[3], wqr[3];   // gather staging, slot = k%3
    uint4 aF[2][2];                              // A prefetch, slot = k&1
    f32x4 acc0 = {0.f, 0.f, 0.f, 0.f};
    f32x4 acc1 = {0.f, 0.f, 0.f, 0.f};

    auto stage = [&](int k) {
        const int sl = k % 3;
        const int m  = k * TP + gpx;
        const int4 av = smpa[m];
        wqr[sl] = smpw[m];
        s0[sl] = *(const uint4*)(xb + av.x + co);
        s1[sl] = *(const uint4*)(xb + av.y + co);
        s2[sl] = *(const uint4*)(xb + av.z + co);
        s3[sl] = *(const uint4*)(xb + av.w + co);
    };
    auto loadA = [&](int k) {
        const int sl = k & 1;
        aF[sl][0] = ab[(k * 2 + 0) * 64];
        aF[sl][1] = ab[(k * 2 + 1) * 64];
    };
    auto blend = [&](int k) {
        const int sl = k % 3;
        const __half2 w00 = u2h(wqr[sl].x), w01 = u2h(wqr[sl].y);
        const __half2 w10 = u2h(wqr[sl].z), w11 = u2h(wqr[sl].w);
        uint4 res;
        unsigned* rp = (unsigned*)&res;
        #pragma unroll
        for (int q = 0; q < 4; ++q) {
            __half2 a = __hmul2(w00, u2h(((const unsigned*)&s0[sl])[q]));
            a = __hfma2(w01, u2h(((const unsigned*)&s1[sl])[q]), a);
            a = __hfma2(w10, u2h(((const unsigned*)&s2[sl])[q]), a);
            a = __hfma2(w11, u2h(((const unsigned*)&s3[sl])[q]), a);
            rp[q] = *(const unsigned*)&a;
        }
        vbuf[sl][oct * TP + gpx] = res;
    };
    auto mfma = [&](int k) {
        const int sl = k % 3;
        #pragma unroll
        for (int kl = 0; kl < 2; ++kl) {
            const int octr = kl * 4 + hi;
            union { uint4 u; f16x8 h; } a, b0, b1;
            a.u  = aF[k & 1][kl];
            b0.u = vbuf[sl][octr * TP + lr];
            b1.u = vbuf[sl][octr * TP + 16 + lr];
            acc0 = __builtin_amdgcn_mfma_f32_16x16x32_f16(a.h, b0.h, acc0, 0, 0, 0);
            acc1 = __builtin_amdgcn_mfma_f32_16x16x32_f16(a.h, b1.h, acc1, 0, 0, 0);
        }
    };

    // prologue: 3 chunks of gather in flight + A(0)
    stage(0); stage(1); stage(2);
    loadA(0);
    blend(0);
    lds_barrier();

    #pragma unroll
    for (int k = 0; k < Kk; ++k) {
        if (k < Kk - 3) stage(k + 3);     // keep 12 corner loads in flight
        if (k < Kk - 1) loadA(k + 1);     // A one chunk ahead
        if (k < Kk - 1) blend(k + 1);     // finish oldest staged -> next buffer
        mfma(k);                          // consume current buffer
        lds_barrier();
    }

    // D: col(px)=lr, row(oc within 16)=hi*4+r
    float* ob = out + ((size_t)b * OCn + og * 16 + hi * 4) * NPIX + p0 + lr;
    #pragma unroll
    for (int r = 0; r < 4; ++r) {
        ob[(size_t)r * NPIX]      = acc0[r];
        ob[(size_t)r * NPIX + 16] = acc1[r];
    }
}

extern "C" void kernel_launch(void* const* d_in, const int* in_sizes, int n_in,
                              void* d_out, int out_size, void* d_ws, size_t ws_size,
                              hipStream_t stream) {
    const float* x   = (const float*)d_in[0];
    const float* off = (const float*)d_in[1];
    const float* w   = (const float*)d_in[2];
    float* out = (float*)d_out;
    unsigned short* wh2 = (unsigned short*)d_ws;                    // 73728 B
    unsigned short* xh  = (unsigned short*)((char*)d_ws + 131072);  // 3.21 MB

    hipLaunchKernelGGL(prep_kernel, dim3(392 + 144), dim3(256), 0, stream, x, w, xh, wh2);
    hipLaunchKernelGGL(deform_fused, dim3(Bn * TILES), dim3(256), 0, stream,
                       xh, off, wh2, out);
}